// Round 1
// baseline (337.841 us; speedup 1.0000x reference)
//
#include <hip/hip_runtime.h>
#include <cmath>

// DeepFM: out[b] = sigmoid( deep·w0 + fm·w1 + wide·w2 + b_ffn )
// BS=8192, TS=100, VOCAB=100000, F=64
// w_ffn segments: deep [0,3200)=t*32+k, fm [3200,8150)=triu(i<j), wide [8150,14550)=t*64+f

#define TS 100
#define F  64
#define FD 32
#define NPAD 104            // rows padded to 13*8
#define NT8 13              // 8-row tiles
#define NFM 91              // upper-tri 8x8 tile pairs (ti<=tj)
#define NJOB_FM 182         // x2 f-halves
#define OFF_FM 3200
#define OFF_WIDE 8150

__device__ __forceinline__ int triidx(int i, int j) {
    // index of pair (i,j), i<j, in np.triu_indices(TS, k=1) order
    return i * (2 * TS - 1 - i) / 2 + (j - i - 1);
}

extern "C" __global__ __launch_bounds__(256)
void deepfm_fp32(const int* __restrict__ x,
                 const float* __restrict__ emb,
                 const float* __restrict__ w_deep,
                 const float* __restrict__ b_deep,
                 const float* __restrict__ w_ffn,
                 const float* __restrict__ b_ffn,
                 float* __restrict__ out)
{
    // e_lds: swizzled col4' = c4 ^ (row>>3). Row stride 256B is bank-aligned;
    // fm lanes read different 8-row tiles at the same (r,c4), so only the tile
    // index (row>>3) varies per lane -> swizzle by it to spread banks.
    __shared__ float e_lds[NPAD][F];
    __shared__ float wdT[FD][F];     // w_deep transposed [k][f], same swizzle on k>>3
    __shared__ float red[4];

    const int tid = threadIdx.x;
    const int b   = blockIdx.x;
    const int* xrow = x + b * TS;

    // stage transposed w_deep (8KB, L2-hot across blocks)
    for (int j = tid; j < F * FD; j += 256) {
        int k = j >> 6, f = j & 63;
        int c4 = f >> 2, cr = f & 3;
        wdT[k][((c4 ^ (k >> 3)) << 2) | cr] = w_deep[f * FD + k];
    }
    // gather embedding rows (float4, swizzled), zero the 4 pad rows
    for (int j = tid; j < NPAD * 16; j += 256) {
        int r = j >> 4, c4 = j & 15;
        float4 v = make_float4(0.f, 0.f, 0.f, 0.f);
        if (r < TS)
            v = reinterpret_cast<const float4*>(emb + (size_t)xrow[r] * F)[c4];
        *reinterpret_cast<float4*>(&e_lds[r][(c4 ^ (r >> 3)) << 2]) = v;
    }
    __syncthreads();

    float z = 0.f;

    // unified job space: [0,182) fm 8x8-tile x f-half; [192,244) deep 8tx8k full-f.
    // Rotate mapping per block so the heavy deep wave rotates across SIMDs.
    const int jt = (tid + ((b & 3) << 6)) & 255;

    float acc[8][8];
    #pragma unroll
    for (int r = 0; r < 8; ++r)
        #pragma unroll
        for (int s = 0; s < 8; ++s) acc[r][s] = 0.f;

    if (jt < NJOB_FM) {
        // ---- fm: pairwise dots, 8x8 register tile, half the f-range ----
        int pairIdx = jt >> 1, fh = jt & 1;
        int ti = 0, rem = pairIdx;
        while (rem >= NT8 - ti) { rem -= NT8 - ti; ++ti; }
        int tj = ti + rem;
        int i0 = ti * 8, j0 = tj * 8;
        for (int c4 = fh * 8; c4 < fh * 8 + 8; ++c4) {
            float4 av[8], bv[8];
            #pragma unroll
            for (int r = 0; r < 8; ++r)
                av[r] = *reinterpret_cast<const float4*>(&e_lds[i0 + r][(c4 ^ ti) << 2]);
            #pragma unroll
            for (int s = 0; s < 8; ++s)
                bv[s] = *reinterpret_cast<const float4*>(&e_lds[j0 + s][(c4 ^ tj) << 2]);
            #pragma unroll
            for (int r = 0; r < 8; ++r)
                #pragma unroll
                for (int s = 0; s < 8; ++s)
                    acc[r][s] += av[r].x * bv[s].x + av[r].y * bv[s].y
                               + av[r].z * bv[s].z + av[r].w * bv[s].w;
        }
        #pragma unroll
        for (int r = 0; r < 8; ++r) {
            int i = i0 + r;
            #pragma unroll
            for (int s = 0; s < 8; ++s) {
                int j = j0 + s;
                if (i < j && j < TS)
                    z += acc[r][s] * w_ffn[OFF_FM + triidx(i, j)];
            }
        }
    } else if (jt >= 192 && jt < 192 + NT8 * 4) {
        // ---- deep: e[100x64] @ w_deep[64x32], 8x8 register tile, full f ----
        int dj = jt - 192;
        int tt = dj >> 2, kt = dj & 3;
        int t0 = tt * 8, k0 = kt * 8;
        for (int c4 = 0; c4 < 16; ++c4) {
            float4 av[8], wv[8];
            #pragma unroll
            for (int r = 0; r < 8; ++r)
                av[r] = *reinterpret_cast<const float4*>(&e_lds[t0 + r][(c4 ^ tt) << 2]);
            #pragma unroll
            for (int s = 0; s < 8; ++s)
                wv[s] = *reinterpret_cast<const float4*>(&wdT[k0 + s][(c4 ^ kt) << 2]);
            #pragma unroll
            for (int r = 0; r < 8; ++r)
                #pragma unroll
                for (int s = 0; s < 8; ++s)
                    acc[r][s] += av[r].x * wv[s].x + av[r].y * wv[s].y
                               + av[r].z * wv[s].z + av[r].w * wv[s].w;
        }
        #pragma unroll
        for (int r = 0; r < 8; ++r) {
            int t = t0 + r;
            if (t < TS) {
                #pragma unroll
                for (int s = 0; s < 8; ++s) {
                    int k = k0 + s;
                    float d = acc[r][s] + b_deep[k];
                    z += fmaxf(d, 0.f) * w_ffn[t * FD + k];
                }
            }
        }
    }

    // ---- wide: e_flat · w_wide ----
    for (int j = tid; j < TS * 16; j += 256) {
        int t = j >> 4, c4 = j & 15;
        float4 v = *reinterpret_cast<const float4*>(&e_lds[t][(c4 ^ (t >> 3)) << 2]);
        const float* w = w_ffn + OFF_WIDE + t * F + c4 * 4;
        z += v.x * w[0] + v.y * w[1] + v.z * w[2] + v.w * w[3];
    }

    // ---- block reduce + sigmoid ----
    #pragma unroll
    for (int off = 32; off > 0; off >>= 1) z += __shfl_down(z, off, 64);
    if ((tid & 63) == 0) red[tid >> 6] = z;
    __syncthreads();
    if (tid == 0) {
        float t = red[0] + red[1] + red[2] + red[3] + b_ffn[0];
        out[b] = 1.f / (1.f + expf(-t));
    }
}

extern "C" void kernel_launch(void* const* d_in, const int* in_sizes, int n_in,
                              void* d_out, int out_size, void* d_ws, size_t ws_size,
                              hipStream_t stream) {
    const int*   x      = (const int*)  d_in[0];
    const float* emb    = (const float*)d_in[1];
    const float* w_deep = (const float*)d_in[2];
    const float* b_deep = (const float*)d_in[3];
    const float* w_ffn  = (const float*)d_in[4];
    const float* b_ffn  = (const float*)d_in[5];
    float* out = (float*)d_out;
    const int bs = in_sizes[0] / TS;   // 8192
    hipLaunchKernelGGL(deepfm_fp32, dim3(bs), dim3(256), 0, stream,
                       x, emb, w_deep, b_deep, w_ffn, b_ffn, out);
}

// Round 3
// 155.030 us; speedup vs baseline: 2.1792x; 2.1792x over previous
//
#include <hip/hip_runtime.h>
#include <cmath>

// DeepFM via bf16 MFMA. out[b] = sigmoid(deep + fm + wide + b_ffn)
// BS=8192, TS=100, F=64, FD=32
// w_ffn: deep [0,3200)=t*32+k | fm [3200,8150)=triu i<j | wide [8150,14550)=t*64+f

#define TS 100
#define F  64
#define FD 32
#define RP 112              // rows padded to 7*16
#define OFF_FM 3200
#define OFF_WIDE 8150
#define NFM_T 28            // upper-tri 16x16 tile pairs (ti<=tj), 7 row tiles
#define NUNITS 42           // 28 fm + 14 deep (7 row x 2 col tiles)
#define VOCAB 100000

typedef __attribute__((ext_vector_type(8))) short short8;
typedef __attribute__((ext_vector_type(4))) float f32x4;

__device__ __forceinline__ ushort f2bf(float x) {       // RN fp32->bf16
    uint u = __float_as_uint(x);
    u = (u + 0x7FFFu + ((u >> 16) & 1u)) >> 16;
    return (ushort)u;
}
__device__ __forceinline__ float bf2f(ushort h) {
    return __uint_as_float((uint)h << 16);
}
__device__ __forceinline__ int triidx(int i, int j) {   // i<j pairs, row-major
    return i * (199 - i) / 2 + (j - i - 1);
}
// Fragment load: 8 consecutive bf16 at row, k-offset; XOR-swizzled (G4 fix for
// 128B row stride). Same addressing serves A-frag (M=row) and B-frag (N=row).
__device__ __forceinline__ short8 ldfrag(const ushort* base, int row, int kbyte, int lane) {
    int col = (kbyte + ((lane >> 4) << 4)) ^ ((row & 7) << 4);
    return *reinterpret_cast<const short8*>(
        reinterpret_cast<const char*>(base) + row * 128 + col);
}

__global__ __launch_bounds__(256)
void emb_cvt(const float* __restrict__ src, ushort* __restrict__ dst, int n8) {
    int i = blockIdx.x * 256 + threadIdx.x;
    if (i >= n8) return;
    const float4* s = reinterpret_cast<const float4*>(src) + (size_t)i * 2;
    float4 a = s[0], b = s[1];
    ushort t[8] = { f2bf(a.x), f2bf(a.y), f2bf(a.z), f2bf(a.w),
                    f2bf(b.x), f2bf(b.y), f2bf(b.z), f2bf(b.w) };
    reinterpret_cast<uint4*>(dst)[i] = *reinterpret_cast<const uint4*>(t);
}

template<bool EMBBF>
__global__ __launch_bounds__(256)
void deepfm_mfma(const int* __restrict__ x,
                 const float* __restrict__ embf,
                 const ushort* __restrict__ embh,
                 const float* __restrict__ w_deep,
                 const float* __restrict__ b_deep,
                 const float* __restrict__ w_ffn,
                 const float* __restrict__ b_ffn,
                 float* __restrict__ out)
{
    __shared__ ushort e_lds[RP * F];    // bf16, swizzled, rows 100..111 zero
    __shared__ ushort wdT[FD * F];      // w_deep^T [k_out][f], bf16, swizzled
    __shared__ int    xs[TS];
    __shared__ float  red[4];

    const int tid  = threadIdx.x;
    const int b    = blockIdx.x;
    const int lane = tid & 63;
    const int wave = tid >> 6;

    if (tid < TS) xs[tid] = x[(size_t)b * TS + tid];
    {   // stage w_deep transposed -> bf16 (256 jobs == 256 threads)
        int n = tid & 31, k8 = tid >> 5;
        ushort t[8];
        #pragma unroll
        for (int j = 0; j < 8; ++j) t[j] = f2bf(w_deep[(k8 * 8 + j) * FD + n]);
        int col = (k8 * 16) ^ ((n & 7) << 4);
        *reinterpret_cast<uint4*>(reinterpret_cast<char*>(wdT) + n * 128 + col)
            = *reinterpret_cast<const uint4*>(t);
    }
    __syncthreads();
    // gather embedding rows -> bf16 LDS (16B per job), zero pad rows
    for (int j = tid; j < RP * 8; j += 256) {
        int r = j >> 3, k8 = j & 7;
        int col = (k8 * 16) ^ ((r & 7) << 4);
        char* dst = reinterpret_cast<char*>(e_lds) + r * 128 + col;
        if (r < TS) {
            if (EMBBF) {
                *reinterpret_cast<uint4*>(dst) =
                    *reinterpret_cast<const uint4*>(embh + (size_t)xs[r] * F + k8 * 8);
            } else {
                const float* s = embf + (size_t)xs[r] * F + k8 * 8;
                float4 a = reinterpret_cast<const float4*>(s)[0];
                float4 c = reinterpret_cast<const float4*>(s)[1];
                ushort t[8] = { f2bf(a.x), f2bf(a.y), f2bf(a.z), f2bf(a.w),
                                f2bf(c.x), f2bf(c.y), f2bf(c.z), f2bf(c.w) };
                *reinterpret_cast<uint4*>(dst) = *reinterpret_cast<const uint4*>(t);
            }
        } else {
            *reinterpret_cast<uint4*>(dst) = make_uint4(0, 0, 0, 0);
        }
    }
    __syncthreads();

    float z = 0.f;

    // 42 tile-units round-robined over 4 waves; each = 2 MFMAs (K=64)
    for (int u = wave; u < NUNITS; u += 4) {
        f32x4 acc = {0.f, 0.f, 0.f, 0.f};
        if (u < NFM_T) {
            // fm tile (ti<=tj): S = e.e^T, weights mask i<j & bounds
            int ti = 0, rem = u;
            while (rem >= 7 - ti) { rem -= 7 - ti; ++ti; }
            int tj = ti + rem;
            int ar = ti * 16 + (lane & 15), br = tj * 16 + (lane & 15);
            short8 a0 = ldfrag(e_lds, ar, 0, lane);
            short8 b0 = ldfrag(e_lds, br, 0, lane);
            short8 a1 = ldfrag(e_lds, ar, 64, lane);
            short8 b1 = ldfrag(e_lds, br, 64, lane);
            acc = __builtin_amdgcn_mfma_f32_16x16x32_bf16(a0, b0, acc, 0, 0, 0);
            acc = __builtin_amdgcn_mfma_f32_16x16x32_bf16(a1, b1, acc, 0, 0, 0);
            int jc = tj * 16 + (lane & 15);
            #pragma unroll
            for (int r = 0; r < 4; ++r) {
                int i = ti * 16 + ((lane >> 4) << 2) + r;
                if (i < jc && jc < TS)
                    z += acc[r] * w_ffn[OFF_FM + triidx(i, jc)];
            }
        } else {
            // deep tile: D = e @ w_deep, relu, dot with w_ffn[t*32+k]
            int v = u - NFM_T, tt = v >> 1, kt = v & 1;
            int ar = tt * 16 + (lane & 15), br = kt * 16 + (lane & 15);
            short8 a0 = ldfrag(e_lds, ar, 0, lane);
            short8 b0 = ldfrag(wdT, br, 0, lane);
            short8 a1 = ldfrag(e_lds, ar, 64, lane);
            short8 b1 = ldfrag(wdT, br, 64, lane);
            acc = __builtin_amdgcn_mfma_f32_16x16x32_bf16(a0, b0, acc, 0, 0, 0);
            acc = __builtin_amdgcn_mfma_f32_16x16x32_bf16(a1, b1, acc, 0, 0, 0);
            int k = kt * 16 + (lane & 15);
            float bk = b_deep[k];
            #pragma unroll
            for (int r = 0; r < 4; ++r) {
                int t = tt * 16 + ((lane >> 4) << 2) + r;
                if (t < TS) {
                    float d = acc[r] + bk;
                    z += fmaxf(d, 0.f) * w_ffn[t * FD + k];
                }
            }
        }
    }

    // wide: e_flat . w_wide (800 jobs of 8 elems = full F per row)
    for (int j = tid; j < TS * 8; j += 256) {
        int t = j >> 3, k8 = j & 7;
        int col = (k8 * 16) ^ ((t & 7) << 4);
        short8 v = *reinterpret_cast<const short8*>(
            reinterpret_cast<const char*>(e_lds) + t * 128 + col);
        const float* w = w_ffn + OFF_WIDE + t * F + k8 * 8;
        #pragma unroll
        for (int q = 0; q < 8; ++q) z += bf2f((ushort)v[q]) * w[q];
    }

    // block reduce + sigmoid
    #pragma unroll
    for (int off = 32; off > 0; off >>= 1) z += __shfl_down(z, off, 64);
    if ((tid & 63) == 0) red[wave] = z;
    __syncthreads();
    if (tid == 0) {
        float t = red[0] + red[1] + red[2] + red[3] + b_ffn[0];
        out[b] = 1.f / (1.f + expf(-t));
    }
}

extern "C" void kernel_launch(void* const* d_in, const int* in_sizes, int n_in,
                              void* d_out, int out_size, void* d_ws, size_t ws_size,
                              hipStream_t stream) {
    const int*   x      = (const int*)  d_in[0];
    const float* emb    = (const float*)d_in[1];
    const float* w_deep = (const float*)d_in[2];
    const float* b_deep = (const float*)d_in[3];
    const float* w_ffn  = (const float*)d_in[4];
    const float* b_ffn  = (const float*)d_in[5];
    float* out = (float*)d_out;
    const int bs = in_sizes[0] / TS;                    // 8192
    const size_t need = (size_t)VOCAB * F * sizeof(ushort);  // 12.8 MB

    if (ws_size >= need) {
        ushort* embh = (ushort*)d_ws;
        const int n8 = VOCAB * F / 8;                   // 800000
        hipLaunchKernelGGL(emb_cvt, dim3((n8 + 255) / 256), dim3(256), 0, stream,
                           emb, embh, n8);
        hipLaunchKernelGGL((deepfm_mfma<true>), dim3(bs), dim3(256), 0, stream,
                           x, emb, embh, w_deep, b_deep, w_ffn, b_ffn, out);
    } else {
        hipLaunchKernelGGL((deepfm_mfma<false>), dim3(bs), dim3(256), 0, stream,
                           x, emb, (const ushort*)nullptr, w_deep, b_deep, w_ffn, b_ffn, out);
    }
}